// Round 13
// baseline (113.282 us; speedup 1.0000x reference)
//
#include <hip/hip_runtime.h>

// Fused UpFIRDn2d via banded MFMA chain: crop(1) -> +bias -> repeat-up x2 ->
// sep 12-tap FIR -> leaky_relu(0.2)*sqrt(2) -> sep 12-tap FIR -> down x2.
// x: (8,64,130,130) f32; out: (8,64,128,128) f32.
//
// Round 19 = Round 18 resubmitted verbatim (round-18 bench died on container
// acquisition, not the kernel; full algebra re-audit done, no code change).
// Round 18: S3+S4 fusion via transposed S3 (T never touches LDS).
// R15-R17 pinned at 43-44us with no pipe saturated; DS traffic + phase count
// is the remaining reducible quantity. Key layout fact: computing
// T^T = mfma(A = U^T, B = D^T) instead of T = mfma(D, U):
//   - A-frag U^T[m=qq][k=pp] reads Ut EXACTLY like the old B-read (A/B lane
//     maps are identical on gfx950);
//   - B-frag D^T[k=pp][n=a] is byte-identical to the old DA table;
//   - the C-frag (col = a = l15, rows qq = 4q4+i) IS the A-fragment of a
//     16x16x16 MFMA with k = qq = 4q4+j -> S4 consumes T^T from REGISTERS
//     (2 cvt_pk per tile), accumulating Out over nt = 0..4.
// Per wave (amt=w>>1, jt=w&1): 5x{2 MFMA32 + pack + 1 MFMA16}. T^T tiles are
// computed by both jt waves (+64 MFMA/block; MFMA util is 7%, free) and Ut
// is read twice (+24 b128), but this DELETES: 80 ds_write_b16 scatter, 16
// b128 T reads, ~300 VALU pack/addr insts, one barrier, and S4's T-latency
// round-trip. 3 barriers total (P0|S1|S2|fused).
// Carried: R15 pinned windows, R16 compile-time schedules + GAIN folded into
// DA, R17 one-window-per-phase + const dedup, unconditional P0 dwordx4.
//   S1:  B1[r][qq]  = sum_c  X[r][c]   * Gt[c][qq]    Kwin32 (25 tiles)
//   S2:  U [pp][qq] = sum_r  G2[pp][r] * B1[r][qq]    Kwin32 (45 tiles), leaky
//   S3': Tt[qq][a]  = sum_pp U[pp][qq] * D[a][pp]     Kwin64 (40 frag-tiles)
//   S4': Out[a][j]  = sum_qq Tt[qq][a]^T * D2t[qq][j] K=16 x5 (40 MFMA16)
// Edge clipping folded into 2 variants of D (by) and 3 of D2t (bx).

#define GAIN_C 1.4142135623730951f
#define NEG2_C (0.2f - 1.0f)   // leaky residual; GAIN folded into DA table

typedef short v8s __attribute__((ext_vector_type(8)));
typedef short v4s __attribute__((ext_vector_type(4)));
typedef float v4f __attribute__((ext_vector_type(4)));
typedef float f4u __attribute__((ext_vector_type(4), aligned(4)));  // align-4 dwordx4

__device__ __forceinline__ void pinv(v8s& x) { asm volatile("" : "+v"(x)); }
__device__ __forceinline__ void pinv4(v4s& x) { asm volatile("" : "+v"(x)); }

// 16x16x16 bf16 MFMA (K=16, A/B = 4 bf16 = 2 VGPR, C/D = 4 f32).
__device__ __forceinline__ v4f mfma16(v4s a, v4s b, v4f c) {
#if __has_builtin(__builtin_amdgcn_mfma_f32_16x16x16_bf16)
    return __builtin_amdgcn_mfma_f32_16x16x16_bf16(a, b, c, 0, 0, 0);
#elif __has_builtin(__builtin_amdgcn_mfma_f32_16x16x16bf16_1k)
    return __builtin_amdgcn_mfma_f32_16x16x16bf16_1k(a, b, c, 0, 0, 0);
#else
    v4f d;
    asm volatile("v_mfma_f32_16x16x16_bf16 %0, %1, %2, %3"
                 : "=v"(d) : "v"(a), "v"(b), "v"(c));
    return d;
#endif
}

__device__ __forceinline__ int f2bf(float f) {   // fp32 -> bf16 bits (RNE)
    unsigned u = __float_as_uint(f);
    return (int)((u + 0x7FFFu + ((u >> 16) & 1u)) >> 16) & 0xFFFF;
}
__device__ __forceinline__ int pack_bf2(float a, float b) {
#if __has_builtin(__builtin_amdgcn_cvt_pk_bf16_f32)
    typedef __bf16 bf2 __attribute__((ext_vector_type(2)));
    bf2 r = __builtin_amdgcn_cvt_pk_bf16_f32(a, b);
    int o; __builtin_memcpy(&o, &r, 4); return o;
#else
    return f2bf(a) | (f2bf(b) << 16);
#endif
}

// band(x, q): up-conv weight linking local input index x to local up index q.
// qlim/xlim: valid extents of the local windows (cols: 74/43, rows: 138/75).
__device__ float band(int x, int q, int qlim, int xlim, const float* fu) {
    if (q >= qlim || x >= xlim || x < 0) return 0.f;
    int p = q >> 1, d = x - p;
    if (q & 1) {
        if (d < 0 || d > 6) return 0.f;
        if (d == 0) return fu[0];
        if (d == 6) return fu[11];
        return fu[2 * d - 1] + fu[2 * d];
    } else {
        if (d < 0 || d > 5) return 0.f;
        return fu[2 * d] + fu[2 * d + 1];
    }
}
// dband(o, q, v): down-conv weight, out index o, up index q; variant v:
// 0 = first tile (zero q<5), 2 = last tile (zero q>=qlim-5). qlim = up extent.
__device__ float dband(int o, int q, int v, int qlim, const float* fd) {
    if (q >= qlim || q < 0) return 0.f;
    if (v == 0 && q < 5) return 0.f;
    if (v == 2 && q >= qlim - 5) return 0.f;
    int k = q - 2 * o;
    if (k < 0 || k > 11) return 0.f;
    return fd[k];
}

// ws layout (bf16):
//   GtB 5nt x512             @0      (cols up: qlim 74, xlim 43, k0=min(8nt,16))
//   G2A 9mt x512             @2560   (rows up: qlim 138, xlim 75, k0=min(8mt,48))
//   DA  2v x (4amt x 2kt)x512 @7168  (rows dn: qlim 138, k0=min(32amt,80)),
//       PRE-SCALED by GAIN_C. Serves as D^T B-operand (A/B lane maps match).
//   D2B16 3v x (5nt x 2jt)x256 @15360 (cols dn, 16x16x16-B layout:
//       lane(n=j=16jt+l15), k=qq=16nt+4q4+jj)
// Total 23040 shorts.  (Keep in sync with consumer kernel!)
__global__ __launch_bounds__(256) void build_consts(
    const float* __restrict__ fu, const float* __restrict__ fd,
    short* __restrict__ ws)
{
    int idx = blockIdx.x * 256 + threadIdx.x;   // grid covers 23040 exactly
    float val;
    if (idx < 15360) {
        int l = (idx >> 3) & 63, j = idx & 7;
        int l15 = l & 15, kq = (l >> 4) * 8 + j;
        if (idx < 2560) {                     // GtB: B-op, frag = nt
            int nt = idx >> 9;
            int k0 = 8 * nt < 16 ? 8 * nt : 16;
            val = band(k0 + kq, 16 * nt + l15, 74, 43, fu);
        } else if (idx < 7168) {              // G2A: A-op, frag = mt (0..8)
            int mt = (idx - 2560) >> 9;
            int k0 = 8 * mt < 48 ? 8 * mt : 48;
            val = band(k0 + kq, 16 * mt + l15, 138, 75, fu);
        } else {                              // DA: frag = (v, amt*2+kt)
            int rel = idx - 7168;
            int v = (rel >> 12) ? 2 : 0;      // by=0 -> v0, by=1 -> v2
            int fi = (rel & 4095) >> 9;
            int amt = fi >> 1, kt = fi & 1;
            int k0 = 32 * amt < 80 ? 32 * amt : 80;
            val = dband(16 * amt + l15, k0 + 32 * kt + kq, v, 138, fd) * GAIN_C;
        }
    } else {                                  // D2B16: frag = (v, nt*2+jt)
        int rel = idx - 15360;                // [0, 7680)
        int v = rel / 2560, r2 = rel - v * 2560;
        int frag = r2 >> 8;                   // 0..9
        int nt = frag >> 1, jt = frag & 1;
        int lane = (r2 & 255) >> 2, jj = r2 & 3;
        int o = 16 * jt + (lane & 15);        // out col j (local 0..31)
        int q = 16 * nt + (lane >> 4) * 4 + jj;   // qq
        val = dband(o, q, v, 74, fd);
    }
    ws[idx] = (short)f2bf(val);
}

#define XPITCH 48    // Xl  [80 r][48 c]    24 words/row (period-4, 2-way: free)
#define BPITCH 88    // B1t [80 qq][88 r]   44 words/row (period-8)
#define UPITCH 152   // Ut  [80 qq][152 pp] 76 words/row (period-8)

// ---- Full-phase pinned windows (R17). VMEM first, then LDS, pin, compute. ----
template<int BASE, int N>
__device__ __forceinline__ void s1_window(
    const short* __restrict__ GtB, const short* __restrict__ Xl,
    short* __restrict__ B1t, int lane, int l15, int q4)
{
    v8s bf[N], a[N];
#pragma unroll
    for (int i = 0; i < N; ++i) {              // VMEM first
        const int t = BASE + i;
        const int nt = t - (t / 5) * 5;
        bf[i] = *(const v8s*)&GtB[nt * 512 + lane * 8];
    }
#pragma unroll
    for (int i = 0; i < N; ++i) {              // then LDS
        const int t = BASE + i;
        const int mt = t / 5, nt = t - mt * 5;
        const int k0 = 8 * nt < 16 ? 8 * nt : 16;
        a[i] = *(const v8s*)&Xl[(16 * mt + l15) * XPITCH + k0 + q4 * 8];
    }
#pragma unroll
    for (int i = 0; i < N; ++i) { pinv(bf[i]); pinv(a[i]); }
#pragma unroll
    for (int i = 0; i < N; ++i) {
        const int t = BASE + i;
        const int mt = t / 5, nt = t - mt * 5;
        v4f acc = {0.f, 0.f, 0.f, 0.f};
        acc = __builtin_amdgcn_mfma_f32_16x16x32_bf16(a[i], bf[i], acc, 0, 0, 0);
        // C: col = qq = 16nt+l15, rows r = 16mt + q4*4 + i
        *(int2*)&B1t[(16 * nt + l15) * BPITCH + 16 * mt + q4 * 4] =
            make_int2(pack_bf2(acc[0], acc[1]), pack_bf2(acc[2], acc[3]));
    }
}

template<int BASE, int N>
__device__ __forceinline__ void s2_window(
    const short* __restrict__ G2A, const short* __restrict__ B1t,
    short* __restrict__ Ut, int lane, int l15, int q4)
{
    constexpr int MT0 = BASE / 5;
    constexpr int MTL = (BASE + N - 1) / 5;     // <= MT0+1 for N<=6
    v8s af0, af1{};
    af0 = *(const v8s*)&G2A[MT0 * 512 + lane * 8];          // VMEM, dedup'd
    if constexpr (MTL != MT0)
        af1 = *(const v8s*)&G2A[MTL * 512 + lane * 8];
    v8s b[N];
#pragma unroll
    for (int i = 0; i < N; ++i) {              // LDS
        const int t = BASE + i;
        const int mt = t / 5, nt = t - mt * 5;
        const int k0 = 8 * mt < 48 ? 8 * mt : 48;
        b[i] = *(const v8s*)&B1t[(16 * nt + l15) * BPITCH + k0 + q4 * 8];
    }
    pinv(af0);
    if constexpr (MTL != MT0) pinv(af1);
#pragma unroll
    for (int i = 0; i < N; ++i) pinv(b[i]);
#pragma unroll
    for (int i = 0; i < N; ++i) {
        const int t = BASE + i;
        const int mt = t / 5, nt = t - mt * 5;
        const v8s af = (mt == MT0) ? af0 : af1;   // constexpr-folded select
        v4f acc = {0.f, 0.f, 0.f, 0.f};
        acc = __builtin_amdgcn_mfma_f32_16x16x32_bf16(af, b[i], acc, 0, 0, 0);
        // leaky residual only (GAIN folded into DA): x + (0.2-1)*min(x,0)
#pragma unroll
        for (int j = 0; j < 4; ++j)
            acc[j] = acc[j] + NEG2_C * fminf(acc[j], 0.f);
        // C: col = qq = 16nt+l15, rows pp = 16mt + q4*4 + i
        *(int2*)&Ut[(16 * nt + l15) * UPITCH + 16 * mt + q4 * 4] =
            make_int2(pack_bf2(acc[0], acc[1]), pack_bf2(acc[2], acc[3]));
    }
}

// ---- Fused S3'+S4': wave (amt, jt). Tt = mfma(Ut-frag, DA-frag) transposed;
// ---- its C-frag (lane l15 = a, rows qq = 4q4+i) feeds MFMA16 directly. ----
template<int W>
__device__ __forceinline__ void s34_phase(
    const short* __restrict__ DA, const short* __restrict__ D2B,
    const short* __restrict__ Ut, float* __restrict__ out,
    size_t obase_c, int i0, int j0, int lane, int l15, int q4)
{
    constexpr int amt = W >> 1, jt = W & 1;
    constexpr int k0 = 32 * amt < 80 ? 32 * amt : 80;
    // VMEM: D^T B-frags (2, reused over all nt) + 5 D2 fragments.
    v8s bp0 = *(const v8s*)&DA[(amt * 2 + 0) * 512 + lane * 8];
    v8s bp1 = *(const v8s*)&DA[(amt * 2 + 1) * 512 + lane * 8];
    v4s d2[5];
#pragma unroll
    for (int nt = 0; nt < 5; ++nt)
        d2[nt] = *(const v4s*)&D2B[(nt * 2 + jt) * 256 + lane * 4];
    // LDS: U^T A-frags (10).
    v8s ut0[5], ut1[5];
#pragma unroll
    for (int nt = 0; nt < 5; ++nt) {
        ut0[nt] = *(const v8s*)&Ut[(16 * nt + l15) * UPITCH + k0 + q4 * 8];
        ut1[nt] = *(const v8s*)&Ut[(16 * nt + l15) * UPITCH + k0 + 32 + q4 * 8];
    }
    pinv(bp0); pinv(bp1);
#pragma unroll
    for (int nt = 0; nt < 5; ++nt) { pinv4(d2[nt]); pinv(ut0[nt]); pinv(ut1[nt]); }

    v4f accO = {0.f, 0.f, 0.f, 0.f};
#pragma unroll
    for (int nt = 0; nt < 5; ++nt) {
        // Tt tile (qq-slice 16nt..+15, a-slice 16amt..+15):
        // A = U^T (lane m = l15 = qq-local), B = D^T -> C col = a = l15.
        v4f t = {0.f, 0.f, 0.f, 0.f};
        t = __builtin_amdgcn_mfma_f32_16x16x32_bf16(ut0[nt], bp0, t, 0, 0, 0);
        t = __builtin_amdgcn_mfma_f32_16x16x32_bf16(ut1[nt], bp1, t, 0, 0, 0);
        // C rows qq = 4q4+i == MFMA16 A-frag k = 4q4+j: pack and consume.
        union { int i2[2]; v4s s; } a16;
        a16.i2[0] = pack_bf2(t[0], t[1]);
        a16.i2[1] = pack_bf2(t[2], t[3]);
        accO = mfma16(a16.s, d2[nt], accO);
    }
    // Out C: col = j = l15, rows a = 4q4+i.
    float* op = out + obase_c
              + (size_t)(i0 + 16 * amt + q4 * 4) * 128 + (j0 + 16 * jt + l15);
#pragma unroll
    for (int i = 0; i < 4; ++i) op[i * 128] = accO[i];
}

// ---- Per-phase bodies: ONE window per wave per phase (R17). ----
template<int W>
__device__ __forceinline__ void s1_phase(
    const short* __restrict__ GtB, const short* __restrict__ Xl,
    short* __restrict__ B1t, int lane, int l15, int q4)
{
    if constexpr (W == 0) s1_window<0, 4>(GtB, Xl, B1t, lane, l15, q4);
    else                  s1_window<3 * W + 1, 3>(GtB, Xl, B1t, lane, l15, q4);
}

template<int W>
__device__ __forceinline__ void s2_phase(
    const short* __restrict__ G2A, const short* __restrict__ B1t,
    short* __restrict__ Ut, int lane, int l15, int q4)
{
    if constexpr (W < 5) s2_window<6 * W, 6>(G2A, B1t, Ut, lane, l15, q4);
    else                 s2_window<5 * W + 5, 5>(G2A, B1t, Ut, lane, l15, q4);
}

#define DISP8(CALL)                                                          \
    if      (w == 0) { CALL(0) } else if (w == 1) { CALL(1) }                \
    else if (w == 2) { CALL(2) } else if (w == 3) { CALL(3) }                \
    else if (w == 4) { CALL(4) } else if (w == 5) { CALL(5) }                \
    else if (w == 6) { CALL(6) } else { CALL(7) }

// LDS (shorts): B1t @0 (7040) | Ut @7040 (12160) | Xl aliases Ut head
// (dead after S1, Ut written in S2). No T buffer (S3/S4 fused in-register).
// Total 19200 shorts = 38400 B -> 4 blocks/CU.
__global__ __launch_bounds__(512, 6) void upfirdn_mfma(
    const float* __restrict__ xin_all,
    const float* __restrict__ bias,
    const short* __restrict__ cws,
    float* __restrict__ out)
{
    __shared__ __align__(16) short SH[19200];
    short* B1t = SH;            // [80][88]
    short* Ut  = SH + 7040;     // [80][152]
    short* Xl  = SH + 7040;     // [80][48], dead after S1

    const int tid  = threadIdx.x;
    const int lane = tid & 63, w = tid >> 6;          // 8 waves
    const int l15  = lane & 15, q4 = lane >> 4;
    const int bx = blockIdx.x, by = blockIdx.y, bc = blockIdx.z;
    const int i0 = by * 64, j0 = bx * 32;

    const short* GtB = cws;
    const short* G2A = cws + 2560;
    const short* DA  = cws + 7168  + (by ? 4096 : 0);
    const short* D2B = cws + 15360 + ((bx == 0) ? 0 : (bx == 3) ? 2 : 1) * 2560;

    // ---- Phase 0: load X tile (crop +1, +bias), pads zero. 80 rows x 48
    // cols; 6 threads/row x 8 cols, 480 active. Unconditional dwordx4 pair
    // loads (overhang provably in-bounds); validity by cndmask after load. ----
    if (tid < 480) {
        const int r  = tid / 6, c6 = tid - 6 * r;
        const int gr = i0 - 5 + r;
        int* dst = (int*)Xl + r * 24 + 4 * c6;
        if (r < 75 && (unsigned)gr < 128u) {
            const float* rowp = xin_all + (size_t)bc * (130 * 130)
                              + (gr + 1) * 130 + (j0 - 4) + 8 * c6;
            f4u v0 = *(const f4u*)rowp;
            f4u v1 = *(const f4u*)(rowp + 4);
            const float bv = bias[bc & 63];
            const bool colInt = (bx == 1) | (bx == 2);
            float f[8];
#pragma unroll
            for (int j = 0; j < 8; ++j) {
                const int c = 8 * c6 + j;              // local col 0..47
                bool valid = c < 43;
                if (!colInt) valid = valid && ((unsigned)(j0 - 5 + c) < 128u);
                const float xv = (j < 4) ? v0[j] : v1[j - 4];
                f[j] = valid ? xv + bv : 0.f;
            }
            *(int4*)dst = make_int4(pack_bf2(f[0], f[1]), pack_bf2(f[2], f[3]),
                                    pack_bf2(f[4], f[5]), pack_bf2(f[6], f[7]));
        } else {
            *(int4*)dst = make_int4(0, 0, 0, 0);
        }
    }
    __syncthreads();

    // ---- S1: 25 tiles, one window per wave. ----
#define S1C(W) s1_phase<W>(GtB, Xl, B1t, lane, l15, q4);
    DISP8(S1C)
#undef S1C
    __syncthreads();

    // ---- S2: 45 tiles. ----
#define S2C(W) s2_phase<W>(G2A, B1t, Ut, lane, l15, q4);
    DISP8(S2C)
#undef S2C
    __syncthreads();

    // ---- Fused S3'+S4': no barrier, no T LDS traffic. ----
    const size_t obase_c = (size_t)bc * 16384;
#define S34C(W) s34_phase<W>(DA, D2B, Ut, out, obase_c, i0, j0, lane, l15, q4);
    DISP8(S34C)
#undef S34C
}

extern "C" void kernel_launch(void* const* d_in, const int* in_sizes, int n_in,
                              void* d_out, int out_size, void* d_ws, size_t ws_size,
                              hipStream_t stream) {
    const float* x  = (const float*)d_in[0];
    const float* bs = (const float*)d_in[1];
    const float* fu = (const float*)d_in[2];
    const float* fd = (const float*)d_in[3];
    float* outp = (float*)d_out;
    short* ws = (short*)d_ws;

    build_consts<<<90, 256, 0, stream>>>(fu, fd, ws);    // 23040 elems
    upfirdn_mfma<<<dim3(4, 2, 512), 512, 0, stream>>>(x, bs, ws, outp);
}

// Round 14
// 107.894 us; speedup vs baseline: 1.0499x; 1.0499x over previous
//
#include <hip/hip_runtime.h>

// Fused UpFIRDn2d via banded MFMA chain: crop(1) -> +bias -> repeat-up x2 ->
// sep 12-tap FIR -> leaky_relu(0.2)*sqrt(2) -> sep 12-tap FIR -> down x2.
// x: (8,64,130,130) f32; out: (8,64,128,128) f32.
//
// Round 20 = REVERT to round-17 (best measured: e2e 108.0, main ~44us).
// Round-19's S3+S4 fusion regressed (46.5-47.8us): the fused
// MFMA32->pack->MFMA16 chain is serial IN-WAVE (non-overlappable), doubled
// Ut reads added +390K conflict-cycles; removing the barrier didn't pay.
// Final ledger (R8-R19): occupancy null, barrier-count null, VALU-count null
// x2, ILP pinning -10% (R15), addressing null, window-count null, fusion
// negative. No pipe >55% at the 43-44us floor. Structural constraint: the
// 3-barrier phase chain x LDS/VMEM round-trip latency x 16 sequential
// block-slots/CU. This kernel is the plateau configuration.
//
// Structure: R15 pinned windows (asm "+v" data-dep stops load sinking) +
// R16 compile-time schedules (literal bases, GAIN folded into DA) + R17
// one-window-per-phase + const-frag dedup + unconditional P0 dwordx4.
//   S1: B1[r][qq]  = sum_c  X[r][c]   * Gt[c][qq]    M80  N80  Kwin32 (25 tiles)
//   S2: U [pp][qq] = sum_r  G2[pp][r] * B1[r][qq]    M144 N80  Kwin32 (45), leaky
//   S3: T [a][qq]  = sum_pp D[a][pp]  * U[pp][qq]    M64  N80  Kwin64 (20)
//   S4: Out[a][j]  = sum_qq T[a][qq]  * D2t[qq][j]   M64  N32  Kwin64 (8)
// Edge clipping folded into 2 variants of D (by) and 3 of D2t (bx).

#define GAIN_C 1.4142135623730951f
#define NEG2_C (0.2f - 1.0f)   // leaky residual; GAIN folded into DA table

typedef short v8s __attribute__((ext_vector_type(8)));
typedef float v4f __attribute__((ext_vector_type(4)));
typedef float f4u __attribute__((ext_vector_type(4), aligned(4)));  // align-4 dwordx4

__device__ __forceinline__ void pinv(v8s& x) { asm volatile("" : "+v"(x)); }

__device__ __forceinline__ int f2bf(float f) {   // fp32 -> bf16 bits (RNE)
    unsigned u = __float_as_uint(f);
    return (int)((u + 0x7FFFu + ((u >> 16) & 1u)) >> 16) & 0xFFFF;
}
__device__ __forceinline__ int pack_bf2(float a, float b) {
#if __has_builtin(__builtin_amdgcn_cvt_pk_bf16_f32)
    typedef __bf16 bf2 __attribute__((ext_vector_type(2)));
    bf2 r = __builtin_amdgcn_cvt_pk_bf16_f32(a, b);
    int o; __builtin_memcpy(&o, &r, 4); return o;
#else
    return f2bf(a) | (f2bf(b) << 16);
#endif
}

// band(x, q): up-conv weight linking local input index x to local up index q.
// qlim/xlim: valid extents of the local windows (cols: 74/43, rows: 138/75).
__device__ float band(int x, int q, int qlim, int xlim, const float* fu) {
    if (q >= qlim || x >= xlim || x < 0) return 0.f;
    int p = q >> 1, d = x - p;
    if (q & 1) {
        if (d < 0 || d > 6) return 0.f;
        if (d == 0) return fu[0];
        if (d == 6) return fu[11];
        return fu[2 * d - 1] + fu[2 * d];
    } else {
        if (d < 0 || d > 5) return 0.f;
        return fu[2 * d] + fu[2 * d + 1];
    }
}
// dband(o, q, v): down-conv weight, out index o, up index q; variant v:
// 0 = first tile (zero q<5), 2 = last tile (zero q>=qlim-5). qlim = up extent.
__device__ float dband(int o, int q, int v, int qlim, const float* fd) {
    if (q >= qlim || q < 0) return 0.f;
    if (v == 0 && q < 5) return 0.f;
    if (v == 2 && q >= qlim - 5) return 0.f;
    int k = q - 2 * o;
    if (k < 0 || k > 11) return 0.f;
    return fd[k];
}

// ws layout (bf16):
//   GtB 5nt x512            @0       (cols up: qlim 74, xlim 43, k0=min(8nt,16))
//   G2A 9mt x512            @2560    (rows up: qlim 138, xlim 75, k0=min(8mt,48))
//   DA  2v x (4mt x 2kt)x512 @7168   (rows dn: qlim 138, k0=min(32mt,80)),
//       PRE-SCALED by GAIN_C (leaky gain folded out of S2)
//   D2B 3v x (2nt x 2kt)x512 @15360  (cols dn: qlim 74,  k0=nt?16:0)
// Total 21504 shorts.  (Keep in sync with consumer kernel!)
__global__ __launch_bounds__(256) void build_consts(
    const float* __restrict__ fu, const float* __restrict__ fd,
    short* __restrict__ ws)
{
    int idx = blockIdx.x * 256 + threadIdx.x;   // grid covers 21504 exactly
    int l = (idx >> 3) & 63, j = idx & 7;
    int l15 = l & 15, kq = (l >> 4) * 8 + j;
    float val;
    if (idx < 2560) {                         // GtB: B-op, frag = nt
        int nt = idx >> 9;
        int k0 = 8 * nt < 16 ? 8 * nt : 16;
        val = band(k0 + kq, 16 * nt + l15, 74, 43, fu);
    } else if (idx < 7168) {                  // G2A: A-op, frag = mt (0..8)
        int mt = (idx - 2560) >> 9;
        int k0 = 8 * mt < 48 ? 8 * mt : 48;
        val = band(k0 + kq, 16 * mt + l15, 138, 75, fu);
    } else if (idx < 15360) {                 // DA: A-op, frag = (v, mt*2+kt)
        int rel = idx - 7168;
        int v = (rel >> 12) ? 2 : 0;          // by=0 -> v0, by=1 -> v2
        int fi = (rel & 4095) >> 9;
        int mt = fi >> 1, kt = fi & 1;
        int k0 = 32 * mt < 80 ? 32 * mt : 80;
        val = dband(16 * mt + l15, k0 + 32 * kt + kq, v, 138, fd) * GAIN_C;
    } else {                                  // D2B: B-op, frag = (v, nt*2+kt)
        int rel = idx - 15360;
        int v = rel >> 11, fi = (rel & 2047) >> 9;
        int nt = fi >> 1, kt = fi & 1;
        int k0 = nt ? 16 : 0;
        val = dband(16 * nt + l15, k0 + 32 * kt + kq, v, 74, fd);
    }
    ws[idx] = (short)f2bf(val);
}

#define XPITCH 48    // Xl  [80 r][48 c]    24 words/row (period-4, 2-way: free)
#define BPITCH 88    // B1t [80 qq][88 r]   44 words/row (period-8)
#define UPITCH 152   // Ut  [80 qq][152 pp] 76 words/row (period-8)
#define TPITCH 88    // T   [64 a][88 qq]

// ---- Full-phase pinned windows. Load order: VMEM consts first (200cy),
// ---- then LDS reads (120cy) -> latencies overlap; pin; then MFMAs+writes. ----
template<int BASE, int N>
__device__ __forceinline__ void s1_window(
    const short* __restrict__ GtB, const short* __restrict__ Xl,
    short* __restrict__ B1t, int lane, int l15, int q4)
{
    v8s bf[N], a[N];
#pragma unroll
    for (int i = 0; i < N; ++i) {              // VMEM first
        const int t = BASE + i;
        const int nt = t - (t / 5) * 5;
        bf[i] = *(const v8s*)&GtB[nt * 512 + lane * 8];
    }
#pragma unroll
    for (int i = 0; i < N; ++i) {              // then LDS
        const int t = BASE + i;
        const int mt = t / 5, nt = t - mt * 5;
        const int k0 = 8 * nt < 16 ? 8 * nt : 16;
        a[i] = *(const v8s*)&Xl[(16 * mt + l15) * XPITCH + k0 + q4 * 8];
    }
#pragma unroll
    for (int i = 0; i < N; ++i) { pinv(bf[i]); pinv(a[i]); }
#pragma unroll
    for (int i = 0; i < N; ++i) {
        const int t = BASE + i;
        const int mt = t / 5, nt = t - mt * 5;
        v4f acc = {0.f, 0.f, 0.f, 0.f};
        acc = __builtin_amdgcn_mfma_f32_16x16x32_bf16(a[i], bf[i], acc, 0, 0, 0);
        // C: col = qq = 16nt+l15, rows r = 16mt + q4*4 + i
        *(int2*)&B1t[(16 * nt + l15) * BPITCH + 16 * mt + q4 * 4] =
            make_int2(pack_bf2(acc[0], acc[1]), pack_bf2(acc[2], acc[3]));
    }
}

template<int BASE, int N>
__device__ __forceinline__ void s2_window(
    const short* __restrict__ G2A, const short* __restrict__ B1t,
    short* __restrict__ Ut, int lane, int l15, int q4)
{
    constexpr int MT0 = BASE / 5;
    constexpr int MTL = (BASE + N - 1) / 5;     // <= MT0+1 for N<=6
    v8s af0, af1{};
    af0 = *(const v8s*)&G2A[MT0 * 512 + lane * 8];          // VMEM, dedup'd
    if constexpr (MTL != MT0)
        af1 = *(const v8s*)&G2A[MTL * 512 + lane * 8];
    v8s b[N];
#pragma unroll
    for (int i = 0; i < N; ++i) {              // LDS
        const int t = BASE + i;
        const int mt = t / 5, nt = t - mt * 5;
        const int k0 = 8 * mt < 48 ? 8 * mt : 48;
        b[i] = *(const v8s*)&B1t[(16 * nt + l15) * BPITCH + k0 + q4 * 8];
    }
    pinv(af0);
    if constexpr (MTL != MT0) pinv(af1);
#pragma unroll
    for (int i = 0; i < N; ++i) pinv(b[i]);
#pragma unroll
    for (int i = 0; i < N; ++i) {
        const int t = BASE + i;
        const int mt = t / 5, nt = t - mt * 5;
        const v8s af = (mt == MT0) ? af0 : af1;   // constexpr-folded select
        v4f acc = {0.f, 0.f, 0.f, 0.f};
        acc = __builtin_amdgcn_mfma_f32_16x16x32_bf16(af, b[i], acc, 0, 0, 0);
        // leaky residual only (GAIN folded into DA): x + (0.2-1)*min(x,0)
#pragma unroll
        for (int j = 0; j < 4; ++j)
            acc[j] = acc[j] + NEG2_C * fminf(acc[j], 0.f);
        // C: col = qq = 16nt+l15, rows pp = 16mt + q4*4 + i
        *(int2*)&Ut[(16 * nt + l15) * UPITCH + 16 * mt + q4 * 4] =
            make_int2(pack_bf2(acc[0], acc[1]), pack_bf2(acc[2], acc[3]));
    }
}

template<int BASE, int N>
__device__ __forceinline__ void s3_window(
    const short* __restrict__ DA, const short* __restrict__ Ut,
    short* __restrict__ T, int lane, int l15, int q4)
{
    constexpr int MT0 = BASE / 5;
    constexpr int MTL = (BASE + N - 1) / 5;
    v8s a00, a01, a10{}, a11{};
    a00 = *(const v8s*)&DA[(MT0 * 2 + 0) * 512 + lane * 8];  // VMEM, dedup'd
    a01 = *(const v8s*)&DA[(MT0 * 2 + 1) * 512 + lane * 8];
    if constexpr (MTL != MT0) {
        a10 = *(const v8s*)&DA[(MTL * 2 + 0) * 512 + lane * 8];
        a11 = *(const v8s*)&DA[(MTL * 2 + 1) * 512 + lane * 8];
    }
    v8s b0[N], b1[N];
#pragma unroll
    for (int i = 0; i < N; ++i) {              // LDS
        const int t = BASE + i;
        const int mt = t / 5, nt = t - mt * 5;
        const int k0 = 32 * mt < 80 ? 32 * mt : 80;
        b0[i] = *(const v8s*)&Ut[(16 * nt + l15) * UPITCH + k0 + q4 * 8];
        b1[i] = *(const v8s*)&Ut[(16 * nt + l15) * UPITCH + k0 + 32 + q4 * 8];
    }
    pinv(a00); pinv(a01);
    if constexpr (MTL != MT0) { pinv(a10); pinv(a11); }
#pragma unroll
    for (int i = 0; i < N; ++i) { pinv(b0[i]); pinv(b1[i]); }
#pragma unroll
    for (int i = 0; i < N; ++i) {
        const int t = BASE + i;
        const int mt = t / 5, nt = t - mt * 5;
        const v8s a0 = (mt == MT0) ? a00 : a10;   // constexpr-folded
        const v8s a1 = (mt == MT0) ? a01 : a11;
        v4f acc = {0.f, 0.f, 0.f, 0.f};
        acc = __builtin_amdgcn_mfma_f32_16x16x32_bf16(a0, b0[i], acc, 0, 0, 0);
        acc = __builtin_amdgcn_mfma_f32_16x16x32_bf16(a1, b1[i], acc, 0, 0, 0);
        // C: col = qq = 16nt+l15, rows a = 16mt + q4*4 + j  (b16 scatter)
        int p01 = pack_bf2(acc[0], acc[1]);
        int p23 = pack_bf2(acc[2], acc[3]);
        short* tb = &T[(16 * mt + q4 * 4) * TPITCH + 16 * nt + l15];
        tb[0 * TPITCH] = (short)p01;
        tb[1 * TPITCH] = (short)(p01 >> 16);
        tb[2 * TPITCH] = (short)p23;
        tb[3 * TPITCH] = (short)(p23 >> 16);
    }
}

// ---- Per-phase bodies: ONE window per wave per phase. ----
template<int W>
__device__ __forceinline__ void s1_phase(
    const short* __restrict__ GtB, const short* __restrict__ Xl,
    short* __restrict__ B1t, int lane, int l15, int q4)
{
    if constexpr (W == 0) s1_window<0, 4>(GtB, Xl, B1t, lane, l15, q4);
    else                  s1_window<3 * W + 1, 3>(GtB, Xl, B1t, lane, l15, q4);
}

template<int W>
__device__ __forceinline__ void s2_phase(
    const short* __restrict__ G2A, const short* __restrict__ B1t,
    short* __restrict__ Ut, int lane, int l15, int q4)
{
    if constexpr (W < 5) s2_window<6 * W, 6>(G2A, B1t, Ut, lane, l15, q4);
    else                 s2_window<5 * W + 5, 5>(G2A, B1t, Ut, lane, l15, q4);
}

template<int W>
__device__ __forceinline__ void s3_phase(
    const short* __restrict__ DA, const short* __restrict__ Ut,
    short* __restrict__ T, int lane, int l15, int q4)
{
    if constexpr (W < 4) s3_window<3 * W, 3>(DA, Ut, T, lane, l15, q4);
    else                 s3_window<2 * W + 4, 2>(DA, Ut, T, lane, l15, q4);
}

template<int W>
__device__ __forceinline__ void s4_phase(
    const short* __restrict__ T, const short* __restrict__ D2B,
    float* __restrict__ out, size_t obase_c, int i0, int j0, int l15, int q4,
    int lane)
{
    constexpr int mt = W >> 1, nt = W & 1;
    constexpr int k0 = nt ? 16 : 0;
    v8s b0 = *(const v8s*)&D2B[(nt * 2 + 0) * 512 + lane * 8];  // VMEM first
    v8s b1 = *(const v8s*)&D2B[(nt * 2 + 1) * 512 + lane * 8];
    v8s a0 = *(const v8s*)&T[(16 * mt + l15) * TPITCH + k0 + q4 * 8];
    v8s a1 = *(const v8s*)&T[(16 * mt + l15) * TPITCH + k0 + 32 + q4 * 8];
    pinv(b0); pinv(b1); pinv(a0); pinv(a1);
    v4f acc = {0.f, 0.f, 0.f, 0.f};
    acc = __builtin_amdgcn_mfma_f32_16x16x32_bf16(a0, b0, acc, 0, 0, 0);
    acc = __builtin_amdgcn_mfma_f32_16x16x32_bf16(a1, b1, acc, 0, 0, 0);
    float* op = out + obase_c
              + (size_t)(i0 + 16 * mt + q4 * 4) * 128 + (j0 + 16 * nt + l15);
#pragma unroll
    for (int i = 0; i < 4; ++i) op[i * 128] = acc[i];
}

#define DISP8(CALL)                                                          \
    if      (w == 0) { CALL(0) } else if (w == 1) { CALL(1) }                \
    else if (w == 2) { CALL(2) } else if (w == 3) { CALL(3) }                \
    else if (w == 4) { CALL(4) } else if (w == 5) { CALL(5) }                \
    else if (w == 6) { CALL(6) } else { CALL(7) }

// LDS (shorts): B1t @0 (7040) | Ut @7040 (12160) | Xl aliases Ut head
// (dead after S1, Ut written in S2) | T aliases B1t (dead after S2).
// Total 19200 shorts = 38400 B -> 4 blocks/CU.
__global__ __launch_bounds__(512, 6) void upfirdn_mfma(
    const float* __restrict__ xin_all,
    const float* __restrict__ bias,
    const short* __restrict__ cws,
    float* __restrict__ out)
{
    __shared__ __align__(16) short SH[19200];
    short* B1t = SH;            // [80][88]
    short* Ut  = SH + 7040;     // [80][152]
    short* Xl  = SH + 7040;     // [80][48], dead after S1
    short* T   = SH;            // [64][88], written in S3

    const int tid  = threadIdx.x;
    const int lane = tid & 63, w = tid >> 6;          // 8 waves
    const int l15  = lane & 15, q4 = lane >> 4;
    const int bx = blockIdx.x, by = blockIdx.y, bc = blockIdx.z;
    const int i0 = by * 64, j0 = bx * 32;

    const short* GtB = cws;
    const short* G2A = cws + 2560;
    const short* DA  = cws + 7168  + (by ? 4096 : 0);
    const short* D2B = cws + 15360 + ((bx == 0) ? 0 : (bx == 3) ? 2 : 1) * 2048;

    // ---- Phase 0: load X tile (crop +1, +bias), pads zero. 80 rows x 48
    // cols; 6 threads/row x 8 cols, 480 active. Loads are UNCONDITIONAL
    // dwordx4 pairs: absolute index = (gr+1)*130 + (j0-4) + 8*c6 + j with
    // gr+1 in [1,128], overhang <= 5 floats -> always inside the channel's
    // 130x130 allocation. Validity applied by cndmask after load. ----
    if (tid < 480) {
        const int r  = tid / 6, c6 = tid - 6 * r;
        const int gr = i0 - 5 + r;
        int* dst = (int*)Xl + r * 24 + 4 * c6;
        if (r < 75 && (unsigned)gr < 128u) {
            const float* rowp = xin_all + (size_t)bc * (130 * 130)
                              + (gr + 1) * 130 + (j0 - 4) + 8 * c6;
            f4u v0 = *(const f4u*)rowp;
            f4u v1 = *(const f4u*)(rowp + 4);
            const float bv = bias[bc & 63];
            const bool colInt = (bx == 1) | (bx == 2);
            float f[8];
#pragma unroll
            for (int j = 0; j < 8; ++j) {
                const int c = 8 * c6 + j;              // local col 0..47
                bool valid = c < 43;
                if (!colInt) valid = valid && ((unsigned)(j0 - 5 + c) < 128u);
                const float xv = (j < 4) ? v0[j] : v1[j - 4];
                f[j] = valid ? xv + bv : 0.f;
            }
            *(int4*)dst = make_int4(pack_bf2(f[0], f[1]), pack_bf2(f[2], f[3]),
                                    pack_bf2(f[4], f[5]), pack_bf2(f[6], f[7]));
        } else {
            *(int4*)dst = make_int4(0, 0, 0, 0);
        }
    }
    __syncthreads();

    // ---- S1: 25 tiles, one window per wave. ----
#define S1C(W) s1_phase<W>(GtB, Xl, B1t, lane, l15, q4);
    DISP8(S1C)
#undef S1C
    __syncthreads();

    // ---- S2: 45 tiles. ----
#define S2C(W) s2_phase<W>(G2A, B1t, Ut, lane, l15, q4);
    DISP8(S2C)
#undef S2C
    __syncthreads();

    // ---- S3: 20 tiles. ----
#define S3C(W) s3_phase<W>(DA, Ut, T, lane, l15, q4);
    DISP8(S3C)
#undef S3C
    __syncthreads();

    // ---- S4: 8 tiles, one per wave. ----
    const size_t obase_c = (size_t)bc * 16384;
#define S4C(W) s4_phase<W>(T, D2B, out, obase_c, i0, j0, l15, q4, lane);
    DISP8(S4C)
#undef S4C
}

extern "C" void kernel_launch(void* const* d_in, const int* in_sizes, int n_in,
                              void* d_out, int out_size, void* d_ws, size_t ws_size,
                              hipStream_t stream) {
    const float* x  = (const float*)d_in[0];
    const float* bs = (const float*)d_in[1];
    const float* fu = (const float*)d_in[2];
    const float* fd = (const float*)d_in[3];
    float* outp = (float*)d_out;
    short* ws = (short*)d_ws;

    build_consts<<<84, 256, 0, stream>>>(fu, fd, ws);    // 21504 elems
    upfirdn_mfma<<<dim3(4, 2, 512), 512, 0, stream>>>(x, bs, ws, outp);
}